// Round 4
// baseline (274.474 us; speedup 1.0000x reference)
//
#include <hip/hip_runtime.h>
#include <math.h>

// InnerSoftShiftTriple: b=8, c=512 (d=256), h=w=64, N=4096. Hole rows/cols [16,48).
// Round 8: attn occupancy 1 -> 2 workgroups/CU. LDS cut 144 -> 80 KB (single K buffer
// + P buffer, l_acc removed -> global atomics); 160 KB = exactly 2 WGs/CU, 16 waves/CU.
// Two WGs' barriers are independent -> one WG's drain is covered by the other's compute.
// Register diet for 4 waves/SIMD (<=128 incl. MFMA accs): single chained S accumulator
// (16 regs, chain hidden by TLP), F fragments streamed inline in the O loop (no ff[8]
// array). Single-K schedule: stage(it+1) right after the pack barrier, overlapping O.
// norm/build/final unchanged except norm's grid +64 blocks to zero the l accumulators.

typedef float  f32x16 __attribute__((ext_vector_type(16)));
typedef float  f32x4v __attribute__((ext_vector_type(4)));
typedef short  bf16x8 __attribute__((ext_vector_type(8)));
#define MFMA32(a, b, c) __builtin_amdgcn_mfma_f32_32x32x16_bf16(a, b, c, 0, 0, 0)

// out.latter region of batch b (1048576 floats) as shorts:
//   [0, 786432)        KnT_c [3072 keys][256 d]   normalized latter, compacted known
//   [786432, 1572864)  Fc    [256 d][3072 keys]   former bf16, compacted known
//   [1572864, 1835008) Qn    [1024 q][256 d]      normalized latter, hole positions

__device__ __forceinline__ unsigned short f2bf(float f) {
    union { float f; unsigned u; } v; v.f = f;
    unsigned u = v.u + 0x7fffu + ((v.u >> 16) & 1u);   // RNE
    return (unsigned short)(u >> 16);
}

__device__ __forceinline__ void nt_store4(float* p, float a, float b, float c, float d) {
    f32x4v v; v[0] = a; v[1] = b; v[2] = c; v[3] = d;
    __builtin_nontemporal_store(v, (f32x4v*)p);
}

// rcpn[b][n] = 1/(||latter[b,:,n]|| + 1e-8) -> ws[0..32768). blocks >= 1024 zero the
// l accumulators ws[32768..49152) (attn atomicAdds into them).
__global__ void norm_kernel(const float* __restrict__ x, float* __restrict__ ws) {
    if (blockIdx.x >= 1024) {
        int i = (blockIdx.x - 1024) * 256 + threadIdx.x;
        ws[32768 + i] = 0.0f;
        return;
    }
    __shared__ float red[8][33];
    int blk = blockIdx.x;           // 1024 = b(8) x nc(128)
    int b = blk >> 7, nc = blk & 127;
    int t = threadIdx.x;
    int nl = t & 31, dg = t >> 5;
    const float* p = x + (size_t)(b * 512 + 256) * 4096 + nc * 32 + nl;
    float acc = 0.f;
    #pragma unroll 8
    for (int i = 0; i < 32; ++i) { float v = p[(size_t)(dg * 32 + i) * 4096]; acc += v * v; }
    red[dg][nl] = acc;
    __syncthreads();
    if (t < 32) {
        float s = 0.f;
        #pragma unroll
        for (int g = 0; g < 8; ++g) s += red[g][t];
        ws[b * 4096 + nc * 32 + t] = 1.0f / (sqrtf(s) + 1e-8f);
    }
}

// fused: blk<8192 -> former copy (NT) + Fc scratch; else KnT/Qn build
__global__ void build_kernel(const float* __restrict__ x, const float* __restrict__ ws,
                             float* __restrict__ out) {
    int blk = blockIdx.x;
    int t = threadIdx.x;
    if (blk < 8192) {
        int i4 = blk * 256 + t;
        int e = i4 << 2;
        int b = e >> 20, rem = e & 1048575;
        int d = rem >> 12, n = rem & 4095;
        float4 v = *(const float4*)(x + ((size_t)b << 21) + rem);
        nt_store4(out + (size_t)b * 3145728 + rem, v.x, v.y, v.z, v.w);
        int r = n >> 6, c = n & 63;
        bool hole = (r >= 16) && (r < 48) && (c >= 16) && (c < 48);
        if (!hole) {
            int ci;
            if (r < 16) ci = n;
            else if (r >= 48) ci = n - 1024;
            else ci = 1024 + (r - 16) * 32 + (c < 16 ? c : c - 32);
            unsigned short* fc = (unsigned short*)(out + (size_t)b * 3145728 + 1048576) + 786432;
            ushort4 hh; hh.x = f2bf(v.x); hh.y = f2bf(v.y); hh.z = f2bf(v.z); hh.w = f2bf(v.w);
            *(ushort4*)(fc + (size_t)d * 3072 + ci) = hh;
        }
    } else {
        __shared__ float tile[64 * 69];
        int blk2 = blk - 8192;           // 2048 = b(8) x dt(4) x nt(64)
        int b = blk2 >> 8, dt = (blk2 >> 6) & 3, nt = blk2 & 63;
        int d0 = dt << 6, n0 = nt << 6;
        const float* lat = x + (size_t)(b * 512 + 256) * 4096;
        const float* rb  = ws + b * 4096 + n0;
        #pragma unroll
        for (int i = 0; i < 4; ++i) {
            int cc = t + 256 * i;
            int dr = cc >> 4, nc = (cc & 15) << 2;
            float4 v = *(const float4*)(lat + (size_t)(d0 + dr) * 4096 + n0 + nc);
            float4 r = *(const float4*)(rb + nc);
            tile[dr * 69 + nc + 0] = v.x * r.x;
            tile[dr * 69 + nc + 1] = v.y * r.y;
            tile[dr * 69 + nc + 2] = v.z * r.z;
            tile[dr * 69 + nc + 3] = v.w * r.w;
        }
        __syncthreads();
        unsigned short* base16 = (unsigned short*)(out + (size_t)b * 3145728 + 1048576);
        #pragma unroll
        for (int i = 0; i < 2; ++i) {
            int cc = t + 256 * i;
            int nn = cc >> 3, dp = (cc & 7) << 3;
            int n = n0 + nn;
            int r = n >> 6, c = n & 63;
            bool hole = (r >= 16) && (r < 48) && (c >= 16) && (c < 48);
            unsigned short* dst;
            if (hole) {
                dst = base16 + 1572864 + (size_t)((r - 16) * 32 + (c - 16)) * 256 + d0 + dp;
            } else {
                int ci;
                if (r < 16) ci = n;
                else if (r >= 48) ci = n - 1024;
                else ci = 1024 + (r - 16) * 32 + (c < 16 ? c : c - 32);
                dst = base16 + (size_t)ci * 256 + d0 + dp;
            }
            ushort4 h0, h1;
            h0.x = f2bf(tile[(dp + 0) * 69 + nn]); h0.y = f2bf(tile[(dp + 1) * 69 + nn]);
            h0.z = f2bf(tile[(dp + 2) * 69 + nn]); h0.w = f2bf(tile[(dp + 3) * 69 + nn]);
            h1.x = f2bf(tile[(dp + 4) * 69 + nn]); h1.y = f2bf(tile[(dp + 5) * 69 + nn]);
            h1.z = f2bf(tile[(dp + 6) * 69 + nn]); h1.w = f2bf(tile[(dp + 7) * 69 + nn]);
            *(ushort4*)(dst)     = h0;
            *(ushort4*)(dst + 4) = h1;
        }
    }
}

// stage one 128-key chunk [128 k][256 d] bf16 into LDS via global_load_lds width=16.
// Row k = 512B = 32 slots of 16B; phys slot p holds logical slot p ^ (k&31)
// (pre-swizzled GLOBAL source; DMA dest linear: base + lane*16).
__device__ __forceinline__ void stage_k(const unsigned short* __restrict__ knt,
                                        unsigned short* kdst, int kb, int w, int lane) {
    const int l32 = lane & 31, khi = lane >> 5;
    #pragma unroll
    for (int g = 0; g < 8; ++g) {
        const int krow = w * 16 + g * 2;            // wave-uniform (2 keys / instruction)
        const int k = krow + khi;                   // per-lane key
        const unsigned short* gsrc = knt + (size_t)(kb + k) * 256 + ((l32 ^ (k & 31)) << 3);
        __builtin_amdgcn_global_load_lds(
            (const __attribute__((address_space(1))) void*)gsrc,
            (__attribute__((address_space(3))) void*)(kdst + krow * 256),
            16, 0, 0);
    }
}

// grid 256 = b(8) x qt(16) x h(2); 512 threads (8 waves). 64 queries, 1536 keys/block,
// 12 chunks of 128 keys. Single kbuf (64 KB) + pbuf (16 KB) = 80 KB -> 2 WGs/CU.
// Schedule per chunk: S(kbuf)+pack -> barrier -> stage(it+1) DMA + O(pbuf, F inline)
// -> barrier (drains DMA). Waves: qg = w&1 (32-q), ks = w>>1 (32-k slice of 128).
__launch_bounds__(512, 4)
__global__ void attn_kernel(float* __restrict__ out, float* __restrict__ ws) {
    __shared__ __align__(16) unsigned short kbuf[128 * 256];  // 64 KB
    __shared__ __align__(16) unsigned short pbuf[64 * 128];   // 16 KB

    const int tid = threadIdx.x;
    const int w = tid >> 6, lane = tid & 63;
    const int l32 = lane & 31, half = lane >> 5;
    const int bi = blockIdx.x;
    const int b = bi & 7;                 // batch <-> XCD pin
    const int rest = bi >> 3;
    const int qt = rest & 15;
    const int h = rest >> 4;              // key half
    const int qg = w & 1;                 // S-phase q-group (32 q)
    const int ks = w >> 1;                // S-phase key slice (32 k of 128)

    const unsigned short* base16 = (const unsigned short*)(out + (size_t)b * 3145728 + 1048576);
    const unsigned short* knt = base16;
    const unsigned short* fc  = base16 + 786432;
    const unsigned short* qn  = base16 + 1572864;

    // Q resident (B-operand): lane holds q-col = qg*32 + l32, d = j*16 + half*8 + 0..7
    bf16x8 qf[16];
    {
        const unsigned short* qrow = qn + (size_t)(qt * 64 + qg * 32 + l32) * 256 + half * 8;
        #pragma unroll
        for (int j = 0; j < 16; ++j) qf[j] = *(const bf16x8*)(qrow + j * 16);
    }

    f32x16 oc0, oc1;
    #pragma unroll
    for (int r = 0; r < 16; ++r) { oc0[r] = 0.f; oc1[r] = 0.f; }
    float lsum = 0.f;

    const int kb0 = h * 1536;
    const int prow = qg * 32 + l32;       // this lane's P row (q) in S-phase
    const int psw  = prow & 15;

    stage_k(knt, kbuf, kb0, w, lane);
    __syncthreads();                      // chunk 0 resident (barrier drains vmcnt)

    for (int it = 0; it < 12; ++it) {
        const int kb = kb0 + (it << 7);
        // S^T = MFMA(K, Q): rows k = ks*32 + .., cols q = qg*32 + l32.
        // Single chained accumulator (16 regs); chain latency hidden by 4 waves/SIMD.
        f32x16 sacc;
        #pragma unroll
        for (int r = 0; r < 16; ++r) sacc[r] = 0.f;
        const unsigned short* krow = kbuf + (size_t)(ks * 32 + l32) * 256;
        #pragma unroll
        for (int j = 0; j < 16; ++j) {
            const bf16x8 kf = *(const bf16x8*)(krow + (((2 * j + half) ^ l32) << 3));
            sacc = MFMA32(kf, qf[j], sacc);
        }
        // p = exp(s-1) (cosines <= 1: fixed max); lane's 16 p's share one q-row.
        // k = ks*32 + 8g + 4half + {0..3} -> one ds_write_b64 per group g.
        #pragma unroll
        for (int g = 0; g < 4; ++g) {
            float p0 = __expf(sacc[4 * g + 0] - 1.0f);
            float p1 = __expf(sacc[4 * g + 1] - 1.0f);
            float p2 = __expf(sacc[4 * g + 2] - 1.0f);
            float p3 = __expf(sacc[4 * g + 3] - 1.0f);
            lsum += (p0 + p1) + (p2 + p3);
            ushort4 hh; hh.x = f2bf(p0); hh.y = f2bf(p1); hh.z = f2bf(p2); hh.w = f2bf(p3);
            *(ushort4*)(pbuf + prow * 128 + (((ks * 4 + g) ^ psw) << 3) + 4 * half) = hh;
        }
        __syncthreads();                  // P visible; all kbuf reads done
        // DMA next chunk into the (single) kbuf -- overlaps the O-phase below;
        // drained by the end-of-iteration barrier.
        if (it < 11) stage_k(knt, kbuf, kb + 128, w, lane);
        // O += P . F: A rows q = {0,32}+l32, B cols d = w*32+l32. F streamed inline
        // (rolling register window, keeps peak VGPR <= 128 for 4 waves/SIMD).
        const unsigned short* fp = fc + (size_t)(w * 32 + l32) * 3072 + kb + half * 8;
        #pragma unroll
        for (int j = 0; j < 8; ++j) {
            const bf16x8 fj = *(const bf16x8*)(fp + j * 16);
            const bf16x8 a0 = *(const bf16x8*)(pbuf + l32 * 128
                                               + (((2 * j + half) ^ (l32 & 15)) << 3));
            const bf16x8 a1 = *(const bf16x8*)(pbuf + (l32 + 32) * 128
                                               + (((2 * j + half) ^ (l32 & 15)) << 3));
            oc0 = MFMA32(a0, fj, oc0);
            oc1 = MFMA32(a1, fj, oc1);
        }
        __syncthreads();                  // pbuf reads done; next K chunk resident
    }

    // row sums: halves cover disjoint k-rows of the same q -> one xor-32 add,
    // then the 4 ks-waves accumulate via global atomics (zeroed by norm_kernel).
    {
        float v = lsum + __shfl_xor(lsum, 32);
        if (half == 0)
            atomicAdd(ws + 32768 + (((b * 16 + qt) << 1) + h) * 64 + qg * 32 + l32, v);
    }

    // store unnormalized partials NT: h=0 -> hole cols, h=1 -> scratch cols n=q
    float* obase = out + (size_t)(b * 768 + 512) * 4096;
    const int d = w * 32 + l32;
    #pragma unroll
    for (int tile = 0; tile < 2; ++tile) {
        #pragma unroll
        for (int g = 0; g < 4; ++g) {
            int rowb = 8 * g + 4 * half;
            int n = (h == 0) ? ((16 + qt * 2 + tile) * 64 + 16 + rowb)
                             : (qt * 64 + tile * 32 + rowb);
            float* pdst = obase + (size_t)d * 4096 + n;
            if (tile == 0) nt_store4(pdst, oc0[4*g], oc0[4*g+1], oc0[4*g+2], oc0[4*g+3]);
            else           nt_store4(pdst, oc1[4*g], oc1[4*g+1], oc1[4*g+2], oc1[4*g+3]);
        }
    }
}

// fused: blk<512 -> combine (merge halves, divide by l, zero consumed scratch col);
//        else latter copy + zero non-hole shift cols with n>=1024.
__global__ void final_kernel(const float* __restrict__ x, float* __restrict__ out,
                             const float* __restrict__ ws) {
    int blk = blockIdx.x;
    int t = threadIdx.x;
    if (blk < 512) {
        int b = blk >> 6, qt = (blk >> 2) & 15, dg = blk & 3;   // 8 x 16 x 4
        const float* l0 = ws + 32768 + ((b * 16 + qt) << 1) * 64;
        const float* l1 = l0 + 64;
        int qq = t & 63, ds = t >> 6;
        float linv = 1.0f / (l0[qq] + l1[qq]);
        int tile = qq >> 5, row = qq & 31;
        int nf = (16 + qt * 2 + tile) * 64 + 16 + row;
        int ns = qt * 64 + qq;
        float* obase = out + (size_t)(b * 768 + 512) * 4096;
        #pragma unroll 4
        for (int i = 0; i < 16; ++i) {
            int d = dg * 64 + ds * 16 + i;
            float v0 = obase[(size_t)d * 4096 + nf];
            float v1 = obase[(size_t)d * 4096 + ns];
            __builtin_nontemporal_store((v0 + v1) * linv, obase + (size_t)d * 4096 + nf);
            __builtin_nontemporal_store(0.0f, obase + (size_t)d * 4096 + ns);
        }
    } else {
        int i4 = (blk - 512) * 256 + t;   // 4,194,304 float4s
        int e = i4 << 2;
        if (e < 8388608) {
            int b = e >> 20, rem = e & 1048575;
            const float* src = x + ((size_t)b << 21) + 1048576 + rem;
            float4 v = *(const float4*)src;
            nt_store4(out + (size_t)b * 3145728 + 1048576 + rem, v.x, v.y, v.z, v.w);
        } else {
            int e2 = e - 8388608;
            int b = e2 >> 20, rem = e2 & 1048575;
            int n = rem & 4095;
            if (n >= 1024) {              // n<1024 scratch cols are zeroed by combine
                int r = n >> 6, c = n & 63;
                bool hole = (r >= 16) && (r < 48) && (c >= 16) && (c < 48);
                if (!hole) nt_store4(out + (size_t)b * 3145728 + 2097152 + rem, 0.f, 0.f, 0.f, 0.f);
            }
        }
    }
}

extern "C" void kernel_launch(void* const* d_in, const int* in_sizes, int n_in,
                              void* d_out, int out_size, void* d_ws, size_t ws_size,
                              hipStream_t stream) {
    const float* x = (const float*)d_in[0];
    float* out = (float*)d_out;
    float* ws  = (float*)d_ws;   // [0,32768): rcpn ; [32768,49152): l accumulators

    hipLaunchKernelGGL(norm_kernel,  dim3(1088),  dim3(256), 0, stream, x, ws);
    hipLaunchKernelGGL(build_kernel, dim3(10240), dim3(256), 0, stream, x, ws, out);
    hipLaunchKernelGGL(attn_kernel,  dim3(256),   dim3(512), 0, stream, out, ws);
    hipLaunchKernelGGL(final_kernel, dim3(16896), dim3(256), 0, stream, x, out, ws);
}

// Round 5
// 223.286 us; speedup vs baseline: 1.2292x; 1.2292x over previous
//
#include <hip/hip_runtime.h>
#include <math.h>

// InnerSoftShiftTriple: b=8, c=512 (d=256), h=w=64, N=4096. Hole rows/cols [16,48).
// Round 9: attn reverted verbatim to R7 (best measured: dual K LDS buffers via
// global_load_lds w16 pre-swizzled source, swapped-operand S^T, 2 partial sets,
// VGPR 128, 0 bank conflicts). R8's 2-WG/CU attempt is abandoned: launch_bounds(512,4)
// forced 64 VGPR -> spills (FETCH 26->50 MB) + single-kbuf DMA/read conflicts (393K).
// Single change this round: NT stores removed from the STREAMING kernels (build/final/
// norm) -- the NT rationale (protect L3 from attn's 590 MB re-reads) is obsolete now
// that attn LDS-stages (FETCH 26 MB). A/B: attn keeps its NT stores as control.

typedef float  f32x16 __attribute__((ext_vector_type(16)));
typedef float  f32x4v __attribute__((ext_vector_type(4)));
typedef short  bf16x8 __attribute__((ext_vector_type(8)));
#define MFMA32(a, b, c) __builtin_amdgcn_mfma_f32_32x32x16_bf16(a, b, c, 0, 0, 0)

// out.latter region of batch b (1048576 floats) as shorts:
//   [0, 786432)        KnT_c [3072 keys][256 d]   normalized latter, compacted known
//   [786432, 1572864)  Fc    [256 d][3072 keys]   former bf16, compacted known
//   [1572864, 1835008) Qn    [1024 q][256 d]      normalized latter, hole positions

__device__ __forceinline__ unsigned short f2bf(float f) {
    union { float f; unsigned u; } v; v.f = f;
    unsigned u = v.u + 0x7fffu + ((v.u >> 16) & 1u);   // RNE
    return (unsigned short)(u >> 16);
}

__device__ __forceinline__ void nt_store4(float* p, float a, float b, float c, float d) {
    f32x4v v; v[0] = a; v[1] = b; v[2] = c; v[3] = d;
    __builtin_nontemporal_store(v, (f32x4v*)p);
}

__device__ __forceinline__ void st4(float* p, float a, float b, float c, float d) {
    f32x4v v; v[0] = a; v[1] = b; v[2] = c; v[3] = d;
    *(f32x4v*)p = v;
}

// rcpn[b][n] = 1/(||latter[b,:,n]|| + 1e-8) -> ws[0..32768).
__global__ void norm_kernel(const float* __restrict__ x, float* __restrict__ ws) {
    __shared__ float red[8][33];
    int blk = blockIdx.x;           // 1024 = b(8) x nc(128)
    int b = blk >> 7, nc = blk & 127;
    int t = threadIdx.x;
    int nl = t & 31, dg = t >> 5;
    const float* p = x + (size_t)(b * 512 + 256) * 4096 + nc * 32 + nl;
    float acc = 0.f;
    #pragma unroll 8
    for (int i = 0; i < 32; ++i) { float v = p[(size_t)(dg * 32 + i) * 4096]; acc += v * v; }
    red[dg][nl] = acc;
    __syncthreads();
    if (t < 32) {
        float s = 0.f;
        #pragma unroll
        for (int g = 0; g < 8; ++g) s += red[g][t];
        ws[b * 4096 + nc * 32 + t] = 1.0f / (sqrtf(s) + 1e-8f);
    }
}

// fused: blk<8192 -> former copy + Fc scratch; else KnT/Qn build
__global__ void build_kernel(const float* __restrict__ x, const float* __restrict__ ws,
                             float* __restrict__ out) {
    int blk = blockIdx.x;
    int t = threadIdx.x;
    if (blk < 8192) {
        int i4 = blk * 256 + t;
        int e = i4 << 2;
        int b = e >> 20, rem = e & 1048575;
        int d = rem >> 12, n = rem & 4095;
        float4 v = *(const float4*)(x + ((size_t)b << 21) + rem);
        st4(out + (size_t)b * 3145728 + rem, v.x, v.y, v.z, v.w);
        int r = n >> 6, c = n & 63;
        bool hole = (r >= 16) && (r < 48) && (c >= 16) && (c < 48);
        if (!hole) {
            int ci;
            if (r < 16) ci = n;
            else if (r >= 48) ci = n - 1024;
            else ci = 1024 + (r - 16) * 32 + (c < 16 ? c : c - 32);
            unsigned short* fc = (unsigned short*)(out + (size_t)b * 3145728 + 1048576) + 786432;
            ushort4 hh; hh.x = f2bf(v.x); hh.y = f2bf(v.y); hh.z = f2bf(v.z); hh.w = f2bf(v.w);
            *(ushort4*)(fc + (size_t)d * 3072 + ci) = hh;
        }
    } else {
        __shared__ float tile[64 * 69];
        int blk2 = blk - 8192;           // 2048 = b(8) x dt(4) x nt(64)
        int b = blk2 >> 8, dt = (blk2 >> 6) & 3, nt = blk2 & 63;
        int d0 = dt << 6, n0 = nt << 6;
        const float* lat = x + (size_t)(b * 512 + 256) * 4096;
        const float* rb  = ws + b * 4096 + n0;
        #pragma unroll
        for (int i = 0; i < 4; ++i) {
            int cc = t + 256 * i;
            int dr = cc >> 4, nc = (cc & 15) << 2;
            float4 v = *(const float4*)(lat + (size_t)(d0 + dr) * 4096 + n0 + nc);
            float4 r = *(const float4*)(rb + nc);
            tile[dr * 69 + nc + 0] = v.x * r.x;
            tile[dr * 69 + nc + 1] = v.y * r.y;
            tile[dr * 69 + nc + 2] = v.z * r.z;
            tile[dr * 69 + nc + 3] = v.w * r.w;
        }
        __syncthreads();
        unsigned short* base16 = (unsigned short*)(out + (size_t)b * 3145728 + 1048576);
        #pragma unroll
        for (int i = 0; i < 2; ++i) {
            int cc = t + 256 * i;
            int nn = cc >> 3, dp = (cc & 7) << 3;
            int n = n0 + nn;
            int r = n >> 6, c = n & 63;
            bool hole = (r >= 16) && (r < 48) && (c >= 16) && (c < 48);
            unsigned short* dst;
            if (hole) {
                dst = base16 + 1572864 + (size_t)((r - 16) * 32 + (c - 16)) * 256 + d0 + dp;
            } else {
                int ci;
                if (r < 16) ci = n;
                else if (r >= 48) ci = n - 1024;
                else ci = 1024 + (r - 16) * 32 + (c < 16 ? c : c - 32);
                dst = base16 + (size_t)ci * 256 + d0 + dp;
            }
            ushort4 h0, h1;
            h0.x = f2bf(tile[(dp + 0) * 69 + nn]); h0.y = f2bf(tile[(dp + 1) * 69 + nn]);
            h0.z = f2bf(tile[(dp + 2) * 69 + nn]); h0.w = f2bf(tile[(dp + 3) * 69 + nn]);
            h1.x = f2bf(tile[(dp + 4) * 69 + nn]); h1.y = f2bf(tile[(dp + 5) * 69 + nn]);
            h1.z = f2bf(tile[(dp + 6) * 69 + nn]); h1.w = f2bf(tile[(dp + 7) * 69 + nn]);
            *(ushort4*)(dst)     = h0;
            *(ushort4*)(dst + 4) = h1;
        }
    }
}

// stage one 128-key chunk [128 k][256 d] bf16 into LDS via global_load_lds width=16.
// Row k = 512B = 32 slots of 16B; phys slot p holds logical slot p ^ (k&31)
// (pre-swizzled GLOBAL source; DMA dest linear: base + lane*16).
__device__ __forceinline__ void stage_k(const unsigned short* __restrict__ knt,
                                        unsigned short* kdst, int kb, int w, int lane) {
    const int l32 = lane & 31, khi = lane >> 5;
    #pragma unroll
    for (int g = 0; g < 8; ++g) {
        const int krow = w * 16 + g * 2;            // wave-uniform (2 keys / instruction)
        const int k = krow + khi;                   // per-lane key
        const unsigned short* gsrc = knt + (size_t)(kb + k) * 256 + ((l32 ^ (k & 31)) << 3);
        __builtin_amdgcn_global_load_lds(
            (const __attribute__((address_space(1))) void*)gsrc,
            (__attribute__((address_space(3))) void*)(kdst + krow * 256),
            16, 0, 0);
    }
}

// grid 256 = b(8) x qt(16) x h(2); 512 threads (8 waves). 64 queries, 1536 keys/block,
// 12 chunks of 128 keys. kbuf double-buffered (DMA overlaps S+pack); pbuf single.
// Waves: qg = w&1 (32-q group), ks = w>>1 (32-key slice). Swapped S^T = MFMA(K, Q).
__launch_bounds__(512, 2)
__global__ void attn_kernel(float* __restrict__ out, float* __restrict__ ws) {
    __shared__ __align__(16) unsigned short kbuf[2][128 * 256];  // 2 x 64 KB
    __shared__ __align__(16) unsigned short pbuf[64 * 128];      // 16 KB
    __shared__ float l_acc[64];

    const int tid = threadIdx.x;
    const int w = tid >> 6, lane = tid & 63;
    const int l32 = lane & 31, half = lane >> 5;
    const int bi = blockIdx.x;
    const int b = bi & 7;                 // batch <-> XCD pin
    const int rest = bi >> 3;
    const int qt = rest & 15;
    const int h = rest >> 4;              // key half
    const int qg = w & 1;                 // S-phase q-group (32 q)
    const int ks = w >> 1;                // S-phase key slice (32 k of 128)

    const unsigned short* base16 = (const unsigned short*)(out + (size_t)b * 3145728 + 1048576);
    const unsigned short* knt = base16;
    const unsigned short* fc  = base16 + 786432;
    const unsigned short* qn  = base16 + 1572864;

    if (tid < 64) l_acc[tid] = 0.f;

    // Q resident (B-operand): lane holds q-col = qg*32 + l32, d = j*16 + half*8 + 0..7
    bf16x8 qf[16];
    {
        const unsigned short* qrow = qn + (size_t)(qt * 64 + qg * 32 + l32) * 256 + half * 8;
        #pragma unroll
        for (int j = 0; j < 16; ++j) qf[j] = *(const bf16x8*)(qrow + j * 16);
    }

    f32x16 oc[2];
    #pragma unroll
    for (int r = 0; r < 16; ++r) { oc[0][r] = 0.f; oc[1][r] = 0.f; }
    float lsum = 0.f;

    const int kb0 = h * 1536;
    const int prow = qg * 32 + l32;       // this lane's P row (q) in S-phase
    const int psw  = prow & 15;

    stage_k(knt, kbuf[0], kb0, w, lane);
    __syncthreads();                      // chunk 0 resident (drains vmcnt)

    for (int it = 0; it < 12; ++it) {
        const int kb = kb0 + (it << 7);
        const unsigned short* kcur = kbuf[it & 1];
        // 1. prefetch next chunk into the other buffer (drained at the next barrier)
        if (it < 11) stage_k(knt, kbuf[(it + 1) & 1], kb + 128, w, lane);
        // 2. F frags (global, L2) for the O-phase; latency hidden under S-phase
        bf16x8 ff[8];
        const unsigned short* fp = fc + (size_t)(w * 32 + l32) * 3072 + kb + half * 8;
        #pragma unroll
        for (int j = 0; j < 8; ++j) ff[j] = *(const bf16x8*)(fp + j * 16);
        // 3. S^T = MFMA(K, Q): rows k = ks*32 + .., cols q = qg*32 + l32; 2 chains
        f32x16 s1, s2;
        #pragma unroll
        for (int r = 0; r < 16; ++r) { s1[r] = 0.f; s2[r] = 0.f; }
        const unsigned short* krow = kcur + (size_t)(ks * 32 + l32) * 256;
        #pragma unroll
        for (int j = 0; j < 8; ++j) {
            const bf16x8 kfa = *(const bf16x8*)(krow + (((2 * j + half) ^ l32) << 3));
            const bf16x8 kfb = *(const bf16x8*)(krow + (((2 * (j + 8) + half) ^ l32) << 3));
            s1 = MFMA32(kfa, qf[j], s1);
            s2 = MFMA32(kfb, qf[j + 8], s2);
        }
        // 4. p = exp(s-1) (cosines <= 1: fixed max); lane's 16 p's share one q-row.
        //    k = ks*32 + 8g + 4half + {0..3} -> one ds_write_b64 per group g.
        #pragma unroll
        for (int g = 0; g < 4; ++g) {
            float p0 = __expf(s1[4 * g + 0] + s2[4 * g + 0] - 1.0f);
            float p1 = __expf(s1[4 * g + 1] + s2[4 * g + 1] - 1.0f);
            float p2 = __expf(s1[4 * g + 2] + s2[4 * g + 2] - 1.0f);
            float p3 = __expf(s1[4 * g + 3] + s2[4 * g + 3] - 1.0f);
            lsum += (p0 + p1) + (p2 + p3);
            ushort4 hh; hh.x = f2bf(p0); hh.y = f2bf(p1); hh.z = f2bf(p2); hh.w = f2bf(p3);
            *(ushort4*)(pbuf + prow * 128 + (((ks * 4 + g) ^ psw) << 3) + 4 * half) = hh;
        }
        __syncthreads();                  // P visible; next-chunk DMA + ff drained
        // 5. O += P . F: A rows q = qt2*32 + l32, B cols d = w*32 + l32
        #pragma unroll
        for (int j = 0; j < 8; ++j) {
            const bf16x8 a0 = *(const bf16x8*)(pbuf + (0 * 32 + l32) * 128
                                               + (((2 * j + half) ^ (l32 & 15)) << 3));
            const bf16x8 a1 = *(const bf16x8*)(pbuf + (1 * 32 + l32) * 128
                                               + (((2 * j + half) ^ (l32 & 15)) << 3));
            oc[0] = MFMA32(a0, ff[j], oc[0]);
            oc[1] = MFMA32(a1, ff[j], oc[1]);
        }
        __syncthreads();                  // all P reads done; pbuf free for next pack
    }

    // row sums: halves hold the same q set with disjoint k rows -> one xor-32 add,
    // then sum the 4 ks-waves via LDS atomic.
    {
        float v = lsum + __shfl_xor(lsum, 32);
        if (half == 0) atomicAdd(&l_acc[qg * 32 + l32], v);
    }
    __syncthreads();
    if (tid < 64) {
        ws[32768 + (((b * 16 + qt) << 1) + h) * 64 + tid] = l_acc[tid];
    }

    // store unnormalized partials NT: h=0 -> hole cols, h=1 -> scratch cols n=q
    float* obase = out + (size_t)(b * 768 + 512) * 4096;
    const int d = w * 32 + l32;
    #pragma unroll
    for (int tile = 0; tile < 2; ++tile) {
        #pragma unroll
        for (int g = 0; g < 4; ++g) {
            int rowb = 8 * g + 4 * half;
            int n = (h == 0) ? ((16 + qt * 2 + tile) * 64 + 16 + rowb)
                             : (qt * 64 + tile * 32 + rowb);
            float* pdst = obase + (size_t)d * 4096 + n;
            if (tile == 0) nt_store4(pdst, oc[0][4*g], oc[0][4*g+1], oc[0][4*g+2], oc[0][4*g+3]);
            else           nt_store4(pdst, oc[1][4*g], oc[1][4*g+1], oc[1][4*g+2], oc[1][4*g+3]);
        }
    }
}

// fused: blk<512 -> combine (merge halves, divide by l, zero consumed scratch col);
//        else latter copy + zero non-hole shift cols with n>=1024.
__global__ void final_kernel(const float* __restrict__ x, float* __restrict__ out,
                             const float* __restrict__ ws) {
    int blk = blockIdx.x;
    int t = threadIdx.x;
    if (blk < 512) {
        int b = blk >> 6, qt = (blk >> 2) & 15, dg = blk & 3;   // 8 x 16 x 4
        const float* l0 = ws + 32768 + ((b * 16 + qt) << 1) * 64;
        const float* l1 = l0 + 64;
        int qq = t & 63, ds = t >> 6;
        float linv = 1.0f / (l0[qq] + l1[qq]);
        int tile = qq >> 5, row = qq & 31;
        int nf = (16 + qt * 2 + tile) * 64 + 16 + row;
        int ns = qt * 64 + qq;
        float* obase = out + (size_t)(b * 768 + 512) * 4096;
        #pragma unroll 4
        for (int i = 0; i < 16; ++i) {
            int d = dg * 64 + ds * 16 + i;
            float v0 = obase[(size_t)d * 4096 + nf];
            float v1 = obase[(size_t)d * 4096 + ns];
            obase[(size_t)d * 4096 + nf] = (v0 + v1) * linv;
            obase[(size_t)d * 4096 + ns] = 0.0f;
        }
    } else {
        int i4 = (blk - 512) * 256 + t;   // 4,194,304 float4s
        int e = i4 << 2;
        if (e < 8388608) {
            int b = e >> 20, rem = e & 1048575;
            const float* src = x + ((size_t)b << 21) + 1048576 + rem;
            float4 v = *(const float4*)src;
            st4(out + (size_t)b * 3145728 + 1048576 + rem, v.x, v.y, v.z, v.w);
        } else {
            int e2 = e - 8388608;
            int b = e2 >> 20, rem = e2 & 1048575;
            int n = rem & 4095;
            if (n >= 1024) {              // n<1024 scratch cols are zeroed by combine
                int r = n >> 6, c = n & 63;
                bool hole = (r >= 16) && (r < 48) && (c >= 16) && (c < 48);
                if (!hole) st4(out + (size_t)b * 3145728 + 2097152 + rem, 0.f, 0.f, 0.f, 0.f);
            }
        }
    }
}

extern "C" void kernel_launch(void* const* d_in, const int* in_sizes, int n_in,
                              void* d_out, int out_size, void* d_ws, size_t ws_size,
                              hipStream_t stream) {
    const float* x = (const float*)d_in[0];
    float* out = (float*)d_out;
    float* ws  = (float*)d_ws;   // [0,32768): rcpn ; [32768,49152): l partials

    hipLaunchKernelGGL(norm_kernel,  dim3(1024),  dim3(256), 0, stream, x, ws);
    hipLaunchKernelGGL(build_kernel, dim3(10240), dim3(256), 0, stream, x, ws, out);
    hipLaunchKernelGGL(attn_kernel,  dim3(256),   dim3(512), 0, stream, out, ws);
    hipLaunchKernelGGL(final_kernel, dim3(16896), dim3(256), 0, stream, x, out, ws);
}